// Round 3
// baseline (119.887 us; speedup 1.0000x reference)
//
#include <hip/hip_runtime.h>

// EdgeCompute v11 (DIAGNOSTIC): identical to v10 but launches edge_mlp TWICE
// (idempotent — both runs write identical outputs). Purpose: dur_R3 - dur_R2
// = T_edge exactly. rocprof top-5 only ever shows the harness's 256MiB
// workspace poison-fills (42us @ 80% HBM), so the edge kernel's own duration
// is unobservable from counters; this round converts dur_us into a direct
// per-kernel measurement.
//   dur >= 175us -> T_edge ~90us (kernel-dominated; attack the mystery 30x)
//   125-175us    -> T_edge 30-80us (real headroom; continue optimizing)
//   <= 115us     -> T_edge <= 20us (harness-dominated; declare roofline)
//
// out = sigmoid( relu(|x[s]-x[d]| @ W1 + b1) @ W2 + b2 )
// N_EDGES=640000, D_FEAT=128, HID=64.

#define DF 128
#define HID 64
#define AST 136   // halfs per LDS diff row (272 B = 17*16B)

typedef _Float16 half8   __attribute__((ext_vector_type(8)));
typedef _Float16 half4_t __attribute__((ext_vector_type(4)));
typedef float    floatx4 __attribute__((ext_vector_type(4)));

__device__ __forceinline__ float sigmoidf_(float t) {
    return __builtin_amdgcn_rcpf(1.0f + __expf(-t));
}

// pre-pass: x -> f16 (2.56MB, L2-resident), W1 -> f16 transposed [hid][feat]
__global__ void cvt_pre(const float* __restrict__ x, const float* __restrict__ W1,
                        _Float16* __restrict__ xh, _Float16* __restrict__ w1t, int n4)
{
    const int i = blockIdx.x * blockDim.x + threadIdx.x;
    if (i < n4) {
        float4 v = ((const float4*)x)[i];
        half4_t h = { (_Float16)v.x, (_Float16)v.y, (_Float16)v.z, (_Float16)v.w };
        ((half4_t*)xh)[i] = h;
    }
    if (i < DF * HID) {                      // w1t[h*128+f] = W1[f*64+h]
        const int h = i >> 7, f = i & 127;
        w1t[i] = (_Float16)W1[f * HID + h];
    }
}

#define ROW(idv) *(const half8*)(xh + (size_t)(idv) * DF + goff)

// issue 8 row loads (4 s-rows, 4 d-rows) for batch ids sIv/dIv
#define ISSUE(S, D, sIv, dIv)                                   \
    S##0 = ROW((sIv).x); S##1 = ROW((sIv).y);                   \
    S##2 = ROW((sIv).z); S##3 = ROW((sIv).w);                   \
    D##0 = ROW((dIv).x); D##1 = ROW((dIv).y);                   \
    D##2 = ROW((dIv).z); D##3 = ROW((dIv).w);

// |s - d| -> LDS rows (t*16 + q*4 + p), chunk r16
#define PROC(t, S, D) {                                                        \
    union { half8 h; uint4 u; } U0, U1, U2, U3;                                \
    U0.h = S##0 - D##0; U1.h = S##1 - D##1;                                    \
    U2.h = S##2 - D##2; U3.h = S##3 - D##3;                                    \
    U0.u.x &= 0x7FFF7FFFu; U0.u.y &= 0x7FFF7FFFu;                              \
    U0.u.z &= 0x7FFF7FFFu; U0.u.w &= 0x7FFF7FFFu;                              \
    U1.u.x &= 0x7FFF7FFFu; U1.u.y &= 0x7FFF7FFFu;                              \
    U1.u.z &= 0x7FFF7FFFu; U1.u.w &= 0x7FFF7FFFu;                              \
    U2.u.x &= 0x7FFF7FFFu; U2.u.y &= 0x7FFF7FFFu;                              \
    U2.u.z &= 0x7FFF7FFFu; U2.u.w &= 0x7FFF7FFFu;                              \
    U3.u.x &= 0x7FFF7FFFu; U3.u.y &= 0x7FFF7FFFu;                              \
    U3.u.z &= 0x7FFF7FFFu; U3.u.w &= 0x7FFF7FFFu;                              \
    *(half8*)(ldsw + ((t) * 16 + q * 4 + 0) * AST + goff) = U0.h;              \
    *(half8*)(ldsw + ((t) * 16 + q * 4 + 1) * AST + goff) = U1.h;              \
    *(half8*)(ldsw + ((t) * 16 + q * 4 + 2) * AST + goff) = U2.h;              \
    *(half8*)(ldsw + ((t) * 16 + q * 4 + 3) * AST + goff) = U3.h; }

__global__ __launch_bounds__(256, 2) void edge_mlp_v10(
    const _Float16* __restrict__ xh, const _Float16* __restrict__ w1t,
    const int* __restrict__ idx,
    const float* __restrict__ b1, const float* __restrict__ W2,
    const float* __restrict__ b2,
    float* __restrict__ out, int n_edges, int ngroups, int gstride)
{
    // per-wave diff tile: [64 edges][128 k (+8 pad)] f16 = 17.4KB x 4 waves
    __shared__ __attribute__((aligned(16))) _Float16 lds_d[4][64 * AST];

    const int tid = threadIdx.x;
    const int L   = tid & 63;
    const int r16 = L & 15;                 // frag-read: edge; gather: 16B chunk
    const int q   = L >> 4;                 // frag-read: quad; gather: row-in-quartet
    const int wv  = tid >> 6;
    _Float16* const ldsw = &lds_d[wv][0];

    // ---- A fragments: W1^T [hid=mt*16+r16][k=kb*32+q*8+j] (64 VGPRs) ----
    half8 wf[4][4];
#pragma unroll
    for (int mt = 0; mt < 4; ++mt)
#pragma unroll
        for (int kb = 0; kb < 4; ++kb)
            wf[mt][kb] = *(const half8*)(w1t + (size_t)(mt * 16 + r16) * DF + kb * 32 + q * 8);
#pragma unroll
    for (int mt = 0; mt < 4; ++mt)
#pragma unroll
        for (int kb = 0; kb < 4; ++kb)
            asm volatile("" : "+v"(wf[mt][kb]));

    // epilogue constants at hid = mt*16 + q*4 + r (f16-packed, 8 VGPRs)
    half4_t b1h[4], w2h[4];
#pragma unroll
    for (int mt = 0; mt < 4; ++mt)
#pragma unroll
        for (int r = 0; r < 4; ++r) {
            b1h[mt][r] = (_Float16)b1[mt * 16 + q * 4 + r];
            w2h[mt][r] = (_Float16)W2[mt * 16 + q * 4 + r];
        }
    const float b2v = b2[0];

    const int goff = r16 * 8;    // 16B chunk offset, shared by gather + LDS write
    const int idof = q * 4;      // this lane's 4 contiguous ids per 16-edge batch

    const int g0 = blockIdx.x;

    // ids for tile g0 (8 x int4; one 64B line per load)
    int4 sI0, sI1, sI2, sI3, dI0, dI1, dI2, dI3;
    {
        const int eb = g0 * 256 + wv * 64;
        sI0 = *(const int4*)(idx + eb +  0 + idof);
        sI1 = *(const int4*)(idx + eb + 16 + idof);
        sI2 = *(const int4*)(idx + eb + 32 + idof);
        sI3 = *(const int4*)(idx + eb + 48 + idof);
        dI0 = *(const int4*)(idx + n_edges + eb +  0 + idof);
        dI1 = *(const int4*)(idx + n_edges + eb + 16 + idof);
        dI2 = *(const int4*)(idx + n_edges + eb + 32 + idof);
        dI3 = *(const int4*)(idx + n_edges + eb + 48 + idof);
    }

#pragma unroll 1
    for (int g = g0; g < ngroups; g += gstride) {
        half8 sa0, sa1, sa2, sa3, da0, da1, da2, da3;   // buffer A
        half8 sb0, sb1, sb2, sb3, db0, db1, db2, db3;   // buffer B
        half8 sc0, sc1, sc2, sc3, dc0, dc1, dc2, dc3;   // buffer C

        // batched gather: 3 batches up-front (24 loads in flight)
        ISSUE(sa, da, sI0, dI0);
        ISSUE(sb, db, sI1, dI1);
        ISSUE(sc, dc, sI2, dI2);

        // prefetch ids for the NEXT tile (arrive during MFMA/epilogue)
        int4 sN0, sN1, sN2, sN3, dN0, dN1, dN2, dN3;
        {
            int gn = g + gstride; if (gn >= ngroups) gn = g;
            const int ebn = gn * 256 + wv * 64;
            sN0 = *(const int4*)(idx + ebn +  0 + idof);
            sN1 = *(const int4*)(idx + ebn + 16 + idof);
            sN2 = *(const int4*)(idx + ebn + 32 + idof);
            sN3 = *(const int4*)(idx + ebn + 48 + idof);
            dN0 = *(const int4*)(idx + n_edges + ebn +  0 + idof);
            dN1 = *(const int4*)(idx + n_edges + ebn + 16 + idof);
            dN2 = *(const int4*)(idx + n_edges + ebn + 32 + idof);
            dN3 = *(const int4*)(idx + n_edges + ebn + 48 + idof);
        }

        PROC(0, sa, da);
        ISSUE(sa, da, sI3, dI3);   // batch 3 reuses A regs freed by PROC(0)
        PROC(1, sb, db);
        PROC(2, sc, dc);
        PROC(3, sa, da);

        // ---- MFMA: D[hid 64][edge 64] = W1^T * diff ----
        floatx4 acc[4][4];                  // acc[mt][et]
#pragma unroll
        for (int mt = 0; mt < 4; ++mt)
#pragma unroll
            for (int et = 0; et < 4; ++et)
                acc[mt][et] = (floatx4){0.f, 0.f, 0.f, 0.f};
#pragma unroll
        for (int kb = 0; kb < 4; ++kb) {
#pragma unroll
            for (int et = 0; et < 4; ++et) {
                const half8 bf = *(const half8*)(ldsw + (et * 16 + r16) * AST + kb * 32 + q * 8);
                acc[0][et] = __builtin_amdgcn_mfma_f32_16x16x32_f16(wf[0][kb], bf, acc[0][et], 0, 0, 0);
                acc[1][et] = __builtin_amdgcn_mfma_f32_16x16x32_f16(wf[1][kb], bf, acc[1][et], 0, 0, 0);
                acc[2][et] = __builtin_amdgcn_mfma_f32_16x16x32_f16(wf[2][kb], bf, acc[2][et], 0, 0, 0);
                acc[3][et] = __builtin_amdgcn_mfma_f32_16x16x32_f16(wf[3][kb], bf, acc[3][et], 0, 0, 0);
            }
        }

        // advance id pipeline (row bufs dead; regs free)
        sI0 = sN0; sI1 = sN1; sI2 = sN2; sI3 = sN3;
        dI0 = dN0; dI1 = dN1; dI2 = dN2; dI3 = dN3;

        // ---- epilogue: relu -> *W2 -> reduce over quads -> sigmoid ----
#pragma unroll
        for (int et = 0; et < 4; ++et) {
            float part = 0.f;
#pragma unroll
            for (int mt = 0; mt < 4; ++mt)
#pragma unroll
                for (int r = 0; r < 4; ++r)
                    part = fmaf(fmaxf(acc[mt][et][r] + (float)b1h[mt][r], 0.f),
                                (float)w2h[mt][r], part);
            part += __shfl_xor(part, 16, 64);
            part += __shfl_xor(part, 32, 64);
            if (L < 16)
                out[g * 256 + wv * 64 + et * 16 + L] = sigmoidf_(part + b2v);
        }
    }
}

// fallback / tail
__global__ void edge_naive(const float* __restrict__ x, const int* __restrict__ idx,
                           const float* __restrict__ W1, const float* __restrict__ b1,
                           const float* __restrict__ W2, const float* __restrict__ b2,
                           float* __restrict__ out, int n_edges, int start)
{
    int e = start + blockIdx.x * blockDim.x + threadIdx.x;
    if (e >= n_edges) return;
    int s = idx[e], d = idx[n_edges + e];
    float t = b2[0];
    for (int j = 0; j < HID; ++j) {
        float h = b1[j];
        for (int k = 0; k < DF; ++k)
            h = fmaf(fabsf(x[(size_t)s * DF + k] - x[(size_t)d * DF + k]), W1[(size_t)k * HID + j], h);
        t = fmaf(fmaxf(h, 0.f), W2[j], t);
    }
    out[e] = sigmoidf_(t);
}

extern "C" void kernel_launch(void* const* d_in, const int* in_sizes, int n_in,
                              void* d_out, int out_size, void* d_ws, size_t ws_size,
                              hipStream_t stream) {
    const float* x   = (const float*)d_in[0];
    const int*   idx = (const int*)d_in[1];
    const float* W1  = (const float*)d_in[2];
    const float* b1  = (const float*)d_in[3];
    const float* W2  = (const float*)d_in[4];
    const float* b2  = (const float*)d_in[5];
    float* out = (float*)d_out;

    const int n_edges = in_sizes[1] / 2;      // indices is [2, n_edges]
    const int n_x     = in_sizes[0];
    const int ngroups = n_edges / 256;        // 256 edges per block-tile
    const int rem     = n_edges - ngroups * 256;

    const size_t xh_bytes  = ((size_t)n_x * sizeof(_Float16) + 255) & ~(size_t)255;
    const size_t w1t_bytes = (size_t)DF * HID * sizeof(_Float16);
    const bool ok = (ws_size >= xh_bytes + w1t_bytes) && (n_x % 4 == 0);

    if (ok && ngroups > 0) {
        _Float16* xh  = (_Float16*)d_ws;
        _Float16* w1t = (_Float16*)((char*)d_ws + xh_bytes);
        const int n4 = n_x / 4;
        cvt_pre<<<(n4 + 255) / 256, 256, 0, stream>>>(x, W1, xh, w1t, n4);

        const int grid = ngroups < 512 ? ngroups : 512;   // 2 blocks/CU
        // DIAGNOSTIC: launch twice (idempotent). dur_R3 - dur_R2 = T_edge.
        edge_mlp_v10<<<grid, 256, 0, stream>>>(xh, w1t, idx, b1, W2, b2,
                                               out, n_edges, ngroups, grid);
        edge_mlp_v10<<<grid, 256, 0, stream>>>(xh, w1t, idx, b1, W2, b2,
                                               out, n_edges, ngroups, grid);
        if (rem > 0)
            edge_naive<<<(rem + 63) / 64, 64, 0, stream>>>(x, idx, W1, b1, W2, b2,
                                                           out, n_edges, ngroups * 256);
    } else {
        edge_naive<<<(n_edges + 63) / 64, 64, 0, stream>>>(x, idx, W1, b1, W2, b2,
                                                           out, n_edges, 0);
    }
}

// Round 4
// 97.162 us; speedup vs baseline: 1.2339x; 1.2339x over previous
//
#include <hip/hip_runtime.h>

// EdgeCompute v12: cooperative 64-edge BLOCK tiles -> 4 blocks/CU (2x TLP).
// out = sigmoid( relu(|x[s]-x[d]| @ W1 + b1) @ W2 + b2 )
// N_EDGES=640000, D_FEAT=128, HID=64.
//
// R3 diagnostic: T_edge(warm)=24.5us (double-launch delta), T_edge(cold)
// ~35-45us, harness fixed ~55us (42us poison fill + gaps). v10's 2 waves/
// SIMD (VGPR~240, LDS 69.6KB) starves latency hiding; request-rate floor
// ~17us. v12: 4 waves share one 64-edge diff tile; each wave gathers 16
// edges + computes a 16-hid slice. wf 16 + acc 16 + staging 32 regs ->
// ~110 VGPR, LDS 36KB (2-buf tile + partials) -> 4 blocks/CU. 1 barrier/
// iter; rows(g+1) issued pre-barrier; ids 2 tiles ahead; cross-wave
// epilogue via 2-buf LDS partials, store lags 1 iter. cvt_pre pre-warms
// idx into L3 (poison evicts it; cold first-tile stalls were serial).
// Predict: dur 95.4 -> ~78-84us. Spill (VGPR>128) = failure signal.

#define DF 128
#define HID 64
#define AST 136   // halfs per LDS diff row (272 B): row-step 4 banks -> 2-way (free)

typedef _Float16 half8   __attribute__((ext_vector_type(8)));
typedef float    floatx4 __attribute__((ext_vector_type(4)));

__device__ __forceinline__ float sigmoidf_(float t) {
    return __builtin_amdgcn_rcpf(1.0f + __expf(-t));
}

// pre-pass: x -> f16 (2.56MB), W1 -> f16 transposed [hid][feat], warm idx into L3
__global__ void cvt_pre(const float* __restrict__ x, const float* __restrict__ W1,
                        const int* __restrict__ idx,
                        _Float16* __restrict__ xh, _Float16* __restrict__ w1t,
                        int n4, int ni4)
{
    const int i = blockIdx.x * blockDim.x + threadIdx.x;
    if (i < n4) {
        float4 v = ((const float4*)x)[i];
        union { _Float16 h[4]; ushort2 u2[2]; } hh;
        hh.h[0] = (_Float16)v.x; hh.h[1] = (_Float16)v.y;
        hh.h[2] = (_Float16)v.z; hh.h[3] = (_Float16)v.w;
        *(uint2*)(xh + (size_t)i * 4) = *(uint2*)&hh;
    }
    if (i < DF * HID) {                      // w1t[h*128+f] = W1[f*64+h]
        const int h = i >> 7, f = i & 127;
        w1t[i] = (_Float16)W1[f * HID + h];
    }
    if (i < ni4) {                           // warm idx (read + live-sink)
        int4 t = ((const int4*)idx)[i];
        asm volatile("" :: "v"(t.x), "v"(t.y), "v"(t.z), "v"(t.w));
    }
}

#define ROW(idv) *(const half8*)(xh + (size_t)(idv) * DF + goff)

__global__ __launch_bounds__(256, 4) void edge_mlp_v12(
    const _Float16* __restrict__ xh, const _Float16* __restrict__ w1t,
    const int* __restrict__ idx,
    const float* __restrict__ b1, const float* __restrict__ W2,
    const float* __restrict__ b2,
    float* __restrict__ out, int n_edges, int ngroups, int gstride)
{
    // shared 64-edge diff tile, double-buffered: 2 x 64 x 136 x 2B = 34.8KB
    __shared__ __attribute__((aligned(16))) _Float16 lds_d[2][64 * AST];
    // cross-wave epilogue partials [buf][wave][edge], 2KB
    __shared__ float lds_p[2][4][64];

    const int tid = threadIdx.x;
    const int L   = tid & 63;
    const int r16 = L & 15;                 // frag: edge-col / hid-row; gather: 16B chunk
    const int q   = L >> 4;                 // frag: K sub + acc row group; gather: edge-in-4
    const int wv  = tid >> 6;

    // A fragments: W1^T slice [hid = wv*16 + r16][k = kb*32 + q*8 + j] (16 VGPRs)
    half8 wf[4];
#pragma unroll
    for (int kb = 0; kb < 4; ++kb)
        wf[kb] = *(const half8*)(w1t + (size_t)(wv * 16 + r16) * DF + kb * 32 + q * 8);

    // epilogue constants at hid = wv*16 + q*4 + r (8 VGPRs)
    float b1v[4], w2v[4];
#pragma unroll
    for (int r = 0; r < 4; ++r) {
        b1v[r] = b1[wv * 16 + q * 4 + r];
        w2v[r] = W2[wv * 16 + q * 4 + r];
    }
    const float b2v = b2[0];

    const int goff = r16 * 8;               // 16B chunk offset within a 256B row
    const int eoff = wv * 16 + q * 4;       // this lane-group's first edge in the tile

    const int g0 = blockIdx.x;

    // ids(g0) then issue rows(g0); ids(g0+gs) staged behind them
    int4 sI, dI, sN, dN;
    sI = *(const int4*)(idx + g0 * 64 + eoff);
    dI = *(const int4*)(idx + n_edges + g0 * 64 + eoff);

    half8 s0, s1, s2, s3, d0, d1, d2, d3;
    s0 = ROW(sI.x); s1 = ROW(sI.y); s2 = ROW(sI.z); s3 = ROW(sI.w);
    d0 = ROW(dI.x); d1 = ROW(dI.y); d2 = ROW(dI.z); d3 = ROW(dI.w);

    {
        int gn = g0 + gstride; if (gn >= ngroups) gn = g0;
        sI = *(const int4*)(idx + gn * 64 + eoff);
        dI = *(const int4*)(idx + n_edges + gn * 64 + eoff);
    }

    int it = 0, gprev = 0;
#pragma unroll 1
    for (int g = g0; g < ngroups; g += gstride, ++it) {
        _Float16* const bufw = &lds_d[it & 1][0];

        // ---- PROC: |s-d| for this wave's 16 edges -> shared tile rows eoff..eoff+3 ----
        {
            union { half8 h; uint4 u; } U0, U1, U2, U3;
            U0.h = s0 - d0; U1.h = s1 - d1; U2.h = s2 - d2; U3.h = s3 - d3;
            U0.u.x &= 0x7FFF7FFFu; U0.u.y &= 0x7FFF7FFFu;
            U0.u.z &= 0x7FFF7FFFu; U0.u.w &= 0x7FFF7FFFu;
            U1.u.x &= 0x7FFF7FFFu; U1.u.y &= 0x7FFF7FFFu;
            U1.u.z &= 0x7FFF7FFFu; U1.u.w &= 0x7FFF7FFFu;
            U2.u.x &= 0x7FFF7FFFu; U2.u.y &= 0x7FFF7FFFu;
            U2.u.z &= 0x7FFF7FFFu; U2.u.w &= 0x7FFF7FFFu;
            U3.u.x &= 0x7FFF7FFFu; U3.u.y &= 0x7FFF7FFFu;
            U3.u.z &= 0x7FFF7FFFu; U3.u.w &= 0x7FFF7FFFu;
            *(half8*)(bufw + (eoff + 0) * AST + goff) = U0.h;
            *(half8*)(bufw + (eoff + 1) * AST + goff) = U1.h;
            *(half8*)(bufw + (eoff + 2) * AST + goff) = U2.h;
            *(half8*)(bufw + (eoff + 3) * AST + goff) = U3.h;
        }

        // ids(g + 2*gs) — consumed next iteration
        {
            int gn = g + 2 * gstride; if (gn >= ngroups) gn = g;
            sN = *(const int4*)(idx + gn * 64 + eoff);
            dN = *(const int4*)(idx + n_edges + gn * 64 + eoff);
        }

        // ISSUE rows(g+gs): in flight across barrier + MFMA + epilogue
        s0 = ROW(sI.x); s1 = ROW(sI.y); s2 = ROW(sI.z); s3 = ROW(sI.w);
        d0 = ROW(dI.x); d1 = ROW(dI.y); d2 = ROW(dI.z); d3 = ROW(dI.w);

        __syncthreads();   // tile(it) + partials(it-1) visible

        // ---- MFMA: D[hid 16 (this wave)][edge 64] ----
        floatx4 acc[4];
#pragma unroll
        for (int et = 0; et < 4; ++et)
            acc[et] = (floatx4){0.f, 0.f, 0.f, 0.f};
#pragma unroll
        for (int kb = 0; kb < 4; ++kb) {
#pragma unroll
            for (int et = 0; et < 4; ++et) {
                const half8 bf = *(const half8*)(bufw + (et * 16 + r16) * AST + kb * 32 + q * 8);
                acc[et] = __builtin_amdgcn_mfma_f32_16x16x32_f16(wf[kb], bf, acc[et], 0, 0, 0);
            }
        }

        // ---- partial epilogue: relu -> *W2 -> sum this wave's 16 hids ----
        float* const pp = &lds_p[it & 1][wv][0];
#pragma unroll
        for (int et = 0; et < 4; ++et) {
            float p = 0.f;
#pragma unroll
            for (int r = 0; r < 4; ++r)
                p = fmaf(fmaxf(acc[et][r] + b1v[r], 0.f), w2v[r], p);
            p += __shfl_xor(p, 16, 64);
            p += __shfl_xor(p, 32, 64);
            if (L < 16) pp[et * 16 + L] = p;
        }

        // ---- finalize PREVIOUS tile: sum 4 wave-slices, sigmoid, store ----
        if (it > 0 && L < 16) {
            const float* const pq = &lds_p[(it & 1) ^ 1][0][0];
            const int e = wv * 16 + L;
            float v = pq[0 * 64 + e] + pq[1 * 64 + e] + pq[2 * 64 + e] + pq[3 * 64 + e];
            out[gprev * 64 + e] = sigmoidf_(v + b2v);
        }

        gprev = g;
        sI = sN; dI = dN;
    }

    // drain: finalize the last tile
    __syncthreads();
    if (it > 0 && L < 16) {
        const float* const pq = &lds_p[(it & 1) ^ 1][0][0];
        const int e = wv * 16 + L;
        float v = pq[0 * 64 + e] + pq[1 * 64 + e] + pq[2 * 64 + e] + pq[3 * 64 + e];
        out[gprev * 64 + e] = sigmoidf_(v + b2v);
    }
}

// fallback / tail
__global__ void edge_naive(const float* __restrict__ x, const int* __restrict__ idx,
                           const float* __restrict__ W1, const float* __restrict__ b1,
                           const float* __restrict__ W2, const float* __restrict__ b2,
                           float* __restrict__ out, int n_edges, int start)
{
    int e = start + blockIdx.x * blockDim.x + threadIdx.x;
    if (e >= n_edges) return;
    int s = idx[e], d = idx[n_edges + e];
    float t = b2[0];
    for (int j = 0; j < HID; ++j) {
        float h = b1[j];
        for (int k = 0; k < DF; ++k)
            h = fmaf(fabsf(x[(size_t)s * DF + k] - x[(size_t)d * DF + k]), W1[(size_t)k * HID + j], h);
        t = fmaf(fmaxf(h, 0.f), W2[j], t);
    }
    out[e] = sigmoidf_(t);
}

extern "C" void kernel_launch(void* const* d_in, const int* in_sizes, int n_in,
                              void* d_out, int out_size, void* d_ws, size_t ws_size,
                              hipStream_t stream) {
    const float* x   = (const float*)d_in[0];
    const int*   idx = (const int*)d_in[1];
    const float* W1  = (const float*)d_in[2];
    const float* b1  = (const float*)d_in[3];
    const float* W2  = (const float*)d_in[4];
    const float* b2  = (const float*)d_in[5];
    float* out = (float*)d_out;

    const int n_edges = in_sizes[1] / 2;      // indices is [2, n_edges]
    const int n_x     = in_sizes[0];
    const int ngroups = n_edges / 64;         // 64 edges per block-tile
    const int rem     = n_edges - ngroups * 64;

    const size_t xh_bytes  = ((size_t)n_x * sizeof(_Float16) + 255) & ~(size_t)255;
    const size_t w1t_bytes = (size_t)DF * HID * sizeof(_Float16);
    const bool ok = (ws_size >= xh_bytes + w1t_bytes) && (n_x % 4 == 0);

    if (ok && ngroups > 0) {
        _Float16* xh  = (_Float16*)d_ws;
        _Float16* w1t = (_Float16*)((char*)d_ws + xh_bytes);
        const int n4  = n_x / 4;
        const int ni4 = (n_edges * 2) / 4;
        const int pgrid = (n4 > ni4 ? n4 : ni4);
        cvt_pre<<<(pgrid + 255) / 256, 256, 0, stream>>>(x, W1, idx, xh, w1t, n4, ni4);

        const int grid = ngroups < 1024 ? ngroups : 1024;   // 4 blocks/CU
        edge_mlp_v12<<<grid, 256, 0, stream>>>(xh, w1t, idx, b1, W2, b2,
                                               out, n_edges, ngroups, grid);
        if (rem > 0)
            edge_naive<<<(rem + 63) / 64, 64, 0, stream>>>(x, idx, W1, b1, W2, b2,
                                                           out, n_edges, ngroups * 64);
    } else {
        edge_naive<<<(n_edges + 63) / 64, 64, 0, stream>>>(x, idx, W1, b1, W2, b2,
                                                           out, n_edges, 0);
    }
}